// Round 11
// baseline (3370.082 us; speedup 1.0000x reference)
//
#include <hip/hip_runtime.h>
#include <stdint.h>

// SoftNMS (gaussian, sigma=0.5, thr=0.001), N=4096, 2 classes.
// R17: CLASS-MERGED BLOCK, ONE WAVE OF EACH CLASS PER SIMD. R16 (2 redundant
// waves/SIMD) confirmed TLP but sublinearly: redundant waves execute the
// IDENTICAL sim -> correlated stalls (same div/exp/DPP at the same time),
// and each wave adds full issue cost (issue/sel = W x I). Fix: one block of
// 512 threads; waves 0-3 = class 0, waves 4-7 = class 1 (CDNA round-robin
// wave->SIMD: wid%4 -> cls=wid>>2 puts one wave of EACH class on every
// SIMD). The two chains per SIMD are independent -> mutual stall hiding,
// and per-step issue (1 sel of EACH class) ~= today's issue for ONE sel.
// Per class: R15-proven structure verbatim (256 threads, CAP=16, FOLD=4;
// the 256*j<cnt gate makes effective slot work == R16's CAP=8 at cnt~2048).
// Outer loops fused with LDS done-flags (uniform barriers; finished class's
// sim degenerates to did=0 at ~no cost). Falsifiable: if waves map packed
// instead of round-robin, each SIMD gets two same-class waves -> ~2x
// current time; signature -> flip to cls=wid&1 next round.

#define N_BOXES 4096
#define T 512             // block size (both classes)
#define TC 256            // threads per class
#define CAP 16            // slots/thread capacity (worst case: one class owns all)
#define FOLD 4            // candidates folded per lane (TC/64)
#define BOXCAP 2560       // LDS cache capacity per class
#define SCORE_THR 0.001f
#define BMAX 32           // batch cap (u32 hit-bitmask width)

typedef unsigned long long u64;
typedef uint32_t u32;

__device__ __forceinline__ u64 kmax(u64 a, u64 b) { return a > b ? a : b; }
__device__ __forceinline__ u64 kmin(u64 a, u64 b) { return a < b ? a : b; }

// LLVM gfx9 wave64 reduction sequence; identity 0, inputs non-negative.
__device__ __forceinline__ int wave_max_nonneg(int v) {
    v = max(v, __builtin_amdgcn_update_dpp(0, v, 0x111, 0xf, 0xf, false)); // row_shr:1
    v = max(v, __builtin_amdgcn_update_dpp(0, v, 0x112, 0xf, 0xf, false)); // row_shr:2
    v = max(v, __builtin_amdgcn_update_dpp(0, v, 0x114, 0xf, 0xf, false)); // row_shr:4
    v = max(v, __builtin_amdgcn_update_dpp(0, v, 0x118, 0xf, 0xf, false)); // row_shr:8
    v = max(v, __builtin_amdgcn_update_dpp(0, v, 0x142, 0xa, 0xf, false)); // row_bcast:15
    v = max(v, __builtin_amdgcn_update_dpp(0, v, 0x143, 0xc, 0xf, false)); // row_bcast:31
    return __builtin_amdgcn_readlane(v, 63);
}

// exact u64 wave max, two-phase (score bits then tie-break bits).
__device__ __forceinline__ u64 wave_max_u64(u64 x) {
    int hi   = (int)(u32)(x >> 32);
    int hmax = wave_max_nonneg(hi);
    int lom  = (hi == hmax) ? (int)(u32)x : 0;
    int lmax = wave_max_nonneg(lom);
    return ((u64)(u32)hmax << 32) | (u64)(u32)lmax;
}

// uniform-index broadcast (v_readlane; index wave-uniform, all lanes active)
__device__ __forceinline__ float readlane_f(float v, int l) {
    return __uint_as_float((u32)__builtin_amdgcn_readlane((int)__float_as_uint(v), l));
}

// workspace layout (196624 bytes)
#define WS_KEY(ws, c)  ((u64*)((char*)(ws) + (size_t)(c) * 32768))
#define WS_BOX(ws, c)  ((float4*)((char*)(ws) + 65536 + (size_t)(c) * 65536))
#define WS_CNT(ws)     ((int*)((char*)(ws) + 196608))

__launch_bounds__(T, 1)
__global__ void softnms_fused(const float* __restrict__ boxes,
                              const float* __restrict__ scores,
                              const int* __restrict__ labels,
                              void* __restrict__ ws) {
    const int tid  = threadIdx.x;
    const int lane = tid & 63;
    const int wid  = tid >> 6;
    const int cls  = wid >> 2;            // one wave of each class per SIMD
    const int cwid = wid & 3;             // class-local wave id
    const int ctid = cwid * 64 + lane;    // class-local thread id [0,256)

    __shared__ u64    maskw[2][64];       // class-membership bitmask
    __shared__ u32    wordpref[2][64];    // inclusive prefix of popcounts
    __shared__ u64    redG[2][4];         // per-wave max of per-thread 2nd key
    __shared__ u64    cand[2][TC];        // per-thread m1 posting
    __shared__ float4 batchbox[2][BMAX];  // winner boxes of current batch
    __shared__ u32    batchstat[2][BMAX]; // winner statics of current batch
    __shared__ int    doneF[2];           // per-class completion flags
    __shared__ float4 box_lds[2][BOXCAP];
    __shared__ u64    okey_lds[2][BOXCAP];

    // ---- phase 0a: membership bitmask + popcount prefix (per class) ----
    for (int base = 0; base < N_BOXES; base += TC) {
        u64 bal = __ballot(labels[base + ctid] == cls);
        if (lane == 0) maskw[cls][(base >> 6) + cwid] = bal;
    }
    __syncthreads();
    if (cwid == 0) {                      // wave 0 of each class
        u32 v = (u32)__popcll(maskw[cls][lane]);
        #pragma unroll
        for (int d = 1; d < 64; d <<= 1) {
            u32 o = __shfl_up(v, d, 64);
            if (lane >= d) v += o;
        }
        wordpref[cls][lane] = v;
    }
    __syncthreads();
    const int cnt = __builtin_amdgcn_readfirstlane((int)wordpref[cls][63]);

    // ---- phase 0b: rank-select my slots (r = ctid + 256*j) -> regs + LDS ----
    float x1r[CAP], y1r[CAP], x2r[CAP], y2r[CAP], ar[CAP];
    u64 key[CAP];
    const float4* boxes4 = reinterpret_cast<const float4*>(boxes);
    #pragma unroll
    for (int j = 0; j < CAP; ++j) {
        key[j] = 0;
        x1r[j] = 0.0f; y1r[j] = 0.0f; x2r[j] = 0.0f; y2r[j] = 0.0f; ar[j] = 0.0f;
        int r = ctid + TC * j;
        if (r < cnt) {
            int lo = 0, hi = 63;   // smallest word W with wordpref > r
            while (lo < hi) { int mid = (lo + hi) >> 1; if (wordpref[cls][mid] > (u32)r) hi = mid; else lo = mid + 1; }
            int W = lo;
            u32 rb = (W == 0) ? 0u : wordpref[cls][W - 1];
            u32 t = (u32)r - rb;
            u64 x = maskw[cls][W];
            int pos = 0;
            u32 c;
            c = (u32)__popcll(x & 0xFFFFFFFFull); if (t >= c) { pos += 32; t -= c; x >>= 32; }
            c = (u32)__popcll(x & 0xFFFFull);     if (t >= c) { pos += 16; t -= c; x >>= 16; }
            c = (u32)__popcll(x & 0xFFull);       if (t >= c) { pos += 8;  t -= c; x >>= 8; }
            c = (u32)__popcll(x & 0xFull);        if (t >= c) { pos += 4;  t -= c; x >>= 4; }
            c = (u32)__popcll(x & 0x3ull);        if (t >= c) { pos += 2;  t -= c; x >>= 2; }
            c = (u32)__popcll(x & 0x1ull);        if (t >= c) { pos += 1; }
            int g = W * 64 + pos;
            float4 b = boxes4[g];
            x1r[j] = b.x; y1r[j] = b.y; x2r[j] = b.z; y2r[j] = b.w;
            ar[j]  = __fmul_rn(__fsub_rn(b.z, b.x), __fsub_rn(b.w, b.y));
            float s = scores[g];
            // key: score<<32 | (4095-g)<<16 | r   (g: argmax tie-break; r: slot)
            key[j] = ((u64)__float_as_uint(s) << 32)
                   | ((u64)(u32)(4095 - g) << 16) | (u64)(u32)r;
            if (r < BOXCAP) box_lds[cls][r] = b;
        }
    }
    __syncthreads();

    // ---- phase 1: fused per-class guarded batch sims, paired selections ----
    u64*    okey = WS_KEY(ws, cls);
    float4* obox = WS_BOX(ws, cls);
    const bool use_lds = (cnt <= BOXCAP);
    int mcnt = 0;

    for (int outer = 0; outer <= N_BOXES; ++outer) {   // cap: insurance only
        // gather: per-thread top-2 of live keys (u64, branchless)
        u64 m1 = 0, m2 = 0;
        #pragma unroll
        for (int j = 0; j < CAP; ++j) {
            if (TC * j < cnt) {
                u64 kj  = key[j];
                u64 nm1 = kmax(m1, kj);
                m2 = kmax(m2, kmin(m1, kj));
                m1 = nm1;
            }
        }
        u64 wg = wave_max_u64(m2);
        if (lane == 0) redG[cls][cwid] = wg;
        cand[cls][ctid] = m1;
        __syncthreads();                               // B1: posts visible

        // level-2: lane keeps only its max of FOLD candidates; 2nd folds into G
        u64 c1 = 0, c2 = 0;
        #pragma unroll
        for (int q = 0; q < FOLD; ++q) {
            u64 c  = cand[cls][lane + 64 * q];
            u64 n1 = kmax(c1, c);
            c2 = kmax(c2, kmin(c1, c));
            c1 = n1;
        }
        u64 G = kmax(kmax(kmax(redG[cls][0], redG[cls][1]),
                          kmax(redG[cls][2], redG[cls][3])),
                     wave_max_u64(c2));
        const u32 Ghi = (u32)(G >> 32), Glo = (u32)G;

        u32 cscb = (u32)(c1 >> 32);                    // score bits (non-neg)
        u32 cst  = (u32)c1;                            // static (unique)
        float4 cb;
        if (use_lds) cb = box_lds[cls][(int)(c1 & 0xFFFF)];
        else         cb = boxes4[4095 - (int)((c1 >> 16) & 0xFFFF)];
        float car = __fmul_rn(__fsub_rn(cb.z, cb.x), __fsub_rn(cb.w, cb.y));

        u32 hm[CAP];                                   // per-slot hit bitmasks
        #pragma unroll
        for (int j = 0; j < CAP; ++j) hm[j] = 0;

        int did = 0;
        for (;;) {
            // ---- winner 1: wave argmax on score bits (tie path rare) ----
            int h1 = wave_max_nonneg((int)cscb);
            const u32 uh1 = (u32)h1;
            if (uh1 == 0u) break;                      // all dead
            if (uh1 < Ghi) break;                      // guard (fast)
            u64 b1m = __ballot(cscb == uh1);
            u32 ul1; int src1;
            if (__popcll(b1m) == 1) {
                src1 = (int)__builtin_ctzll(b1m);
                ul1  = (u32)__builtin_amdgcn_readlane((int)cst, src1);
            } else {
                int lom = (cscb == uh1) ? (int)cst : 0;
                ul1 = (u32)wave_max_nonneg(lom);
                src1 = (int)__builtin_ctzll(__ballot((cscb == uh1) & (cst == ul1)));
            }
            if (uh1 == Ghi && ul1 <= Glo) break;       // guard (exact)
            if (did == BMAX) break;                    // mask width

            float w1x1 = readlane_f(cb.x, src1);
            float w1y1 = readlane_f(cb.y, src1);
            float w1x2 = readlane_f(cb.z, src1);
            float w1y2 = readlane_f(cb.w, src1);
            float war1 = readlane_f(car,  src1);

            // ---- winner 2 (speculative): masked runner-up ----
            u32 csc2 = (lane == src1) ? 0u : cscb;
            int h2 = wave_max_nonneg((int)csc2);
            const u32 uh2 = (u32)h2;
            bool take2 = false; int src2 = 0; u32 ul2 = 0;
            float w2x1 = 0.0f, w2y1 = 0.0f, w2x2 = 0.0f, w2y2 = 0.0f, war2 = 0.0f;
            if (uh2 != 0u && uh2 >= Ghi && (did + 1) < BMAX) {
                u64 b2m = __ballot(csc2 == uh2);
                if (__popcll(b2m) == 1) {
                    src2 = (int)__builtin_ctzll(b2m);
                    ul2  = (u32)__builtin_amdgcn_readlane((int)cst, src2);
                } else {
                    int lom2 = (csc2 == uh2) ? (int)cst : 0;
                    ul2 = (u32)wave_max_nonneg(lom2);
                    src2 = (int)__builtin_ctzll(__ballot((csc2 == uh2) & (cst == ul2)));
                }
                if (uh2 > Ghi || ul2 > Glo) {
                    w2x1 = readlane_f(cb.x, src2);
                    w2y1 = readlane_f(cb.y, src2);
                    w2x2 = readlane_f(cb.z, src2);
                    w2y2 = readlane_f(cb.w, src2);
                    war2 = readlane_f(car,  src2);
                    // pair valid iff boxes disjoint (covers all ranking-change cases)
                    bool ovl = (w1x2 > w2x1) & (w2x2 > w1x1)
                             & (w1y2 > w2y1) & (w2y2 > w1y1);
                    take2 = !ovl;
                }
            }

            // ---- stage winners: LDS batch arrays + output keys (class leader) ----
            if (ctid == 0) {
                u64 w1k = ((u64)uh1 << 32) | (u64)ul1;
                batchbox[cls][did]  = make_float4(w1x1, w1y1, w1x2, w1y2);
                batchstat[cls][did] = ul1;
                if (use_lds) { if (mcnt < BOXCAP) okey_lds[cls][mcnt] = w1k; }
                else if (mcnt < N_BOXES) { okey[mcnt] = w1k; obox[mcnt] = make_float4(w1x1, w1y1, w1x2, w1y2); }
                if (take2) {
                    u64 w2k = ((u64)uh2 << 32) | (u64)ul2;
                    batchbox[cls][did + 1]  = make_float4(w2x1, w2y1, w2x2, w2y2);
                    batchstat[cls][did + 1] = ul2;
                    if (use_lds) { if (mcnt + 1 < BOXCAP) okey_lds[cls][mcnt + 1] = w2k; }
                    else if (mcnt + 1 < N_BOXES) { okey[mcnt + 1] = w2k; obox[mcnt + 1] = make_float4(w2x1, w2y1, w2x2, w2y2); }
                }
            }

            // ---- candidate decay: d1 (and d2) chains ILP-parallel, applied in order ----
            float i1x1 = fmaxf(w1x1, cb.x);
            float i1y1 = fmaxf(w1y1, cb.y);
            float i1x2 = fminf(w1x2, cb.z);
            float i1y2 = fminf(w1y2, cb.w);
            float iw1  = fmaxf(__fsub_rn(i1x2, i1x1), 0.0f);
            float ih1  = fmaxf(__fsub_rn(i1y2, i1y1), 0.0f);
            float int1 = __fmul_rn(iw1, ih1);
            float den1 = __fadd_rn(__fsub_rn(__fadd_rn(war1, car), int1), 1e-8f);
            float iou1 = int1 / den1;                    // IEEE div
            float d1   = expf(__fmul_rn(-2.0f, __fmul_rn(iou1, iou1)));

            float s0 = __uint_as_float(cscb);
            float n1 = __fmul_rn(s0, d1);
            float k1 = (n1 >= SCORE_THR) ? n1 : 0.0f;
            float a1 = (int1 > 0.0f) ? k1 : s0;
            a1 = (lane == src1) ? 0.0f : a1;
            float res = a1;

            if (take2) {
                float i2x1 = fmaxf(w2x1, cb.x);
                float i2y1 = fmaxf(w2y1, cb.y);
                float i2x2 = fminf(w2x2, cb.z);
                float i2y2 = fminf(w2y2, cb.w);
                float iw2  = fmaxf(__fsub_rn(i2x2, i2x1), 0.0f);
                float ih2  = fmaxf(__fsub_rn(i2y2, i2y1), 0.0f);
                float int2 = __fmul_rn(iw2, ih2);
                float den2 = __fadd_rn(__fsub_rn(__fadd_rn(war2, car), int2), 1e-8f);
                float iou2 = int2 / den2;                // IEEE div
                float d2   = expf(__fmul_rn(-2.0f, __fmul_rn(iou2, iou2)));
                float n2 = __fmul_rn(a1, d2);
                float k2 = (n2 >= SCORE_THR) ? n2 : 0.0f;
                float a2 = (int2 > 0.0f) ? k2 : a1;
                res = (lane == src2) ? 0.0f : a2;
            }
            cscb = __float_as_uint(res);

            // ---- owned-slot hit bits (bodies deferred to replay) ----
            u32 bit1 = 1u << did;
            u32 bit2 = (take2 ? (2u << did) : 0u);
            #pragma unroll
            for (int j = 0; j < CAP; ++j) {
                if (TC * j < cnt) {
                    bool hit1 = (w1x2 > x1r[j]) & (x2r[j] > w1x1)
                              & (w1y2 > y1r[j]) & (y2r[j] > w1y1);
                    u32 h = hit1 ? bit1 : 0u;
                    if (take2) {
                        bool hit2 = (w2x2 > x1r[j]) & (x2r[j] > w2x1)
                                  & (w2y2 > y1r[j]) & (y2r[j] > w2y1);
                        h |= hit2 ? bit2 : 0u;
                    }
                    hm[j] |= h;
                }
            }
            int adv = take2 ? 2 : 1;
            mcnt += adv; did += adv;
        }
        if (ctid == 0) doneF[cls] = (did == 0) ? 1 : 0;
        __syncthreads();                               // B2: batch arrays + flags

        // ---- replay: full exact body on set bits, ascending batch order ----
        #pragma unroll
        for (int j = 0; j < CAP; ++j) {
            if (TC * j < cnt) {
                u32 m = hm[j];
                while (m) {
                    int b = (int)__builtin_ctz(m);
                    m &= (m - 1);
                    float4 wb = batchbox[cls][b];
                    u32   wst = batchstat[cls][b];
                    float wx1 = wb.x, wy1 = wb.y, wx2 = wb.z, wy2 = wb.w;
                    float warea = __fmul_rn(__fsub_rn(wx2, wx1), __fsub_rn(wy2, wy1));
                    u64 kj = key[j];
                    float ix1   = fmaxf(wx1, x1r[j]);
                    float iy1   = fmaxf(wy1, y1r[j]);
                    float ix2   = fminf(wx2, x2r[j]);
                    float iy2   = fminf(wy2, y2r[j]);
                    float iw    = fmaxf(__fsub_rn(ix2, ix1), 0.0f);
                    float ih    = fmaxf(__fsub_rn(iy2, iy1), 0.0f);
                    float inter = __fmul_rn(iw, ih);
                    float denom = __fadd_rn(__fsub_rn(__fadd_rn(warea, ar[j]), inter), 1e-8f);
                    float iou   = inter / denom;                // IEEE div
                    float t2    = __fmul_rn(iou, iou);
                    float decay = expf(__fmul_rn(-2.0f, t2));   // exp(-iou^2/0.5)
                    float sc    = __uint_as_float((u32)(kj >> 32));
                    float ns    = __fmul_rn(sc, decay);
                    bool  app   = (kj != 0) && (inter > 0.0f);
                    u64   nk    = ((u64)__float_as_uint(ns) << 32) | (kj & 0xFFFFFFFFull);
                    u64   upd   = app ? ((ns >= SCORE_THR) ? nk : 0ull) : kj;
                    key[j] = ((u32)kj == wst) ? 0ull : upd;     // winner-zero (static unique)
                }
            }
        }
        if (doneF[0] && doneF[1]) break;               // uniform exit
    }

    // ---- batched flush of staged winners (boxes recovered by rank) ----
    int mfin = (mcnt <= cnt) ? mcnt : cnt;             // clamp: insurance only
    __syncthreads();
    if (use_lds) {
        int fl = (mfin <= BOXCAP) ? mfin : BOXCAP;
        for (int m = ctid; m < fl; m += TC) {
            u64 w = okey_lds[cls][m];
            okey[m] = w;
            obox[m] = box_lds[cls][(int)(w & 0xFFFF)];
        }
    }
    if (ctid == 0) WS_CNT(ws)[cls] = mfin;
}

// merge the two strictly-descending key lists by rank; pad the tail
__global__ void softnms_merge(void* __restrict__ ws, float* __restrict__ out) {
    int k = blockIdx.x * blockDim.x + threadIdx.x;   // 0..4095
    const u64*    keyA = WS_KEY(ws, 0);
    const u64*    keyB = WS_KEY(ws, 1);
    const float4* boxA = WS_BOX(ws, 0);
    const float4* boxB = WS_BOX(ws, 1);
    const int mA = WS_CNT(ws)[0];
    const int mB = WS_CNT(ws)[1];

    float* ob = out;
    float* os = out + N_BOXES * 4;
    float* ol = out + N_BOXES * 5;

    if (k < mA) {
        u64 x = keyA[k];
        int lo = 0, hi = mB;
        while (lo < hi) { int mid = (lo + hi) >> 1; if (keyB[mid] > x) lo = mid + 1; else hi = mid; }
        int pos = k + lo;
        float4 b = boxA[k];
        ob[pos * 4 + 0] = b.x; ob[pos * 4 + 1] = b.y;
        ob[pos * 4 + 2] = b.z; ob[pos * 4 + 3] = b.w;
        os[pos] = __uint_as_float((u32)(x >> 32));
        ol[pos] = 0.0f;
    } else if (k < mA + mB) {
        int i = k - mA;
        u64 x = keyB[i];
        int lo = 0, hi = mA;
        while (lo < hi) { int mid = (lo + hi) >> 1; if (keyA[mid] > x) lo = mid + 1; else hi = mid; }
        int pos = i + lo;
        float4 b = boxB[i];
        ob[pos * 4 + 0] = b.x; ob[pos * 4 + 1] = b.y;
        ob[pos * 4 + 2] = b.z; ob[pos * 4 + 3] = b.w;
        os[pos] = __uint_as_float((u32)(x >> 32));
        ol[pos] = 1.0f;
    } else {
        ob[k * 4 + 0] = 0.0f; ob[k * 4 + 1] = 0.0f;
        ob[k * 4 + 2] = 0.0f; ob[k * 4 + 3] = 0.0f;
        os[k] = 0.0f;
        ol[k] = -1.0f;
    }
}

extern "C" void kernel_launch(void* const* d_in, const int* in_sizes, int n_in,
                              void* d_out, int out_size, void* d_ws, size_t ws_size,
                              hipStream_t stream) {
    const float* boxes  = (const float*)d_in[0];
    const float* scores = (const float*)d_in[1];
    const int*   labels = (const int*)d_in[2];
    float* out = (float*)d_out;
    (void)in_sizes; (void)n_in; (void)out_size; (void)ws_size;
    softnms_fused<<<1, T, 0, stream>>>(boxes, scores, labels, d_ws);
    softnms_merge<<<N_BOXES / 256, 256, 0, stream>>>(d_ws, out);
}

// Round 12
// 1958.167 us; speedup vs baseline: 1.7210x; 1.7210x over previous
//
#include <hip/hip_runtime.h>
#include <stdint.h>

// SoftNMS (gaussian, sigma=0.5, thr=0.001), N=4096, 2 classes.
// R19: REVERT TO R16 + BALLOT-GATED DECAY SKIP. R17 (class-merged single
// block) regressed 2038->3370: halved CUs, CAP=16@512thr -> VGPR 128 +
// 608KB scratch writes, fused-loop coupling. R16 config (2 blocks x 512thr,
// 2 waves/SIMD, CAP=8, VGPR 52) is the measured optimum of this structure.
// New: the candidate-decay div+expf is skipped via wave-uniform ballot when
// NO live non-winner candidate overlaps the winner (P ~ 0.99^63 ~ 0.53):
// bit-exact because the skipped update is the bitwise identity for every
// lane (winner zeroed by the existing select). Applied to d1 and d2.
// Everything else byte-identical to R16 (2038us, absmax 0.0).

#define N_BOXES 4096
#define T 512
#define NWAVE (T / 64)
#define CAP 8             // slots/thread capacity (worst case: one class owns all)
#define FOLD (T / 64)     // candidates folded per lane (8)
#define BOXCAP 2560       // LDS cache capacity (40KB box + 20KB key)
#define SCORE_THR 0.001f
#define BMAX 32           // batch cap (u32 hit-bitmask width)

typedef unsigned long long u64;
typedef uint32_t u32;

__device__ __forceinline__ u64 kmax(u64 a, u64 b) { return a > b ? a : b; }
__device__ __forceinline__ u64 kmin(u64 a, u64 b) { return a < b ? a : b; }

// LLVM gfx9 wave64 reduction sequence; identity 0, inputs non-negative.
__device__ __forceinline__ int wave_max_nonneg(int v) {
    v = max(v, __builtin_amdgcn_update_dpp(0, v, 0x111, 0xf, 0xf, false)); // row_shr:1
    v = max(v, __builtin_amdgcn_update_dpp(0, v, 0x112, 0xf, 0xf, false)); // row_shr:2
    v = max(v, __builtin_amdgcn_update_dpp(0, v, 0x114, 0xf, 0xf, false)); // row_shr:4
    v = max(v, __builtin_amdgcn_update_dpp(0, v, 0x118, 0xf, 0xf, false)); // row_shr:8
    v = max(v, __builtin_amdgcn_update_dpp(0, v, 0x142, 0xa, 0xf, false)); // row_bcast:15
    v = max(v, __builtin_amdgcn_update_dpp(0, v, 0x143, 0xc, 0xf, false)); // row_bcast:31
    return __builtin_amdgcn_readlane(v, 63);
}

// exact u64 wave max, two-phase (score bits then tie-break bits).
__device__ __forceinline__ u64 wave_max_u64(u64 x) {
    int hi   = (int)(u32)(x >> 32);
    int hmax = wave_max_nonneg(hi);
    int lom  = (hi == hmax) ? (int)(u32)x : 0;
    int lmax = wave_max_nonneg(lom);
    return ((u64)(u32)hmax << 32) | (u64)(u32)lmax;
}

// uniform-index broadcast (v_readlane; index wave-uniform, all lanes active)
__device__ __forceinline__ float readlane_f(float v, int l) {
    return __uint_as_float((u32)__builtin_amdgcn_readlane((int)__float_as_uint(v), l));
}

// workspace layout (196624 bytes)
#define WS_KEY(ws, c)  ((u64*)((char*)(ws) + (size_t)(c) * 32768))
#define WS_BOX(ws, c)  ((float4*)((char*)(ws) + 65536 + (size_t)(c) * 65536))
#define WS_CNT(ws)     ((int*)((char*)(ws) + 196608))

__launch_bounds__(T, 1)
__global__ void softnms_fused(const float* __restrict__ boxes,
                              const float* __restrict__ scores,
                              const int* __restrict__ labels,
                              void* __restrict__ ws) {
    const int cls  = blockIdx.x;
    const int tid  = threadIdx.x;
    const int lane = tid & 63;
    const int wid  = tid >> 6;

    __shared__ u64    maskw[64];          // class-membership bitmask
    __shared__ u32    wordpref[64];       // inclusive prefix of popcounts
    __shared__ u64    redG[NWAVE];        // per-wave max of per-thread 2nd key
    __shared__ u64    cand[T];            // per-thread m1 posting (512)
    __shared__ float4 batchbox[BMAX];     // winner boxes of current batch
    __shared__ u32    batchstat[BMAX];    // winner statics of current batch
    __shared__ float4 box_lds[BOXCAP];
    __shared__ u64    okey_lds[BOXCAP];

    // ---- phase 0a: membership bitmask + popcount prefix ----
    for (int base = 0; base < N_BOXES; base += T) {
        u64 bal = __ballot(labels[base + tid] == cls);
        if (lane == 0) maskw[(base >> 6) + wid] = bal;
    }
    __syncthreads();
    if (wid == 0) {
        u32 v = (u32)__popcll(maskw[lane]);
        #pragma unroll
        for (int d = 1; d < 64; d <<= 1) {
            u32 o = __shfl_up(v, d, 64);
            if (lane >= d) v += o;
        }
        wordpref[lane] = v;
    }
    __syncthreads();
    const int cnt = __builtin_amdgcn_readfirstlane((int)wordpref[63]);

    // ---- phase 0b: rank-select my slots (r = tid + T*j) -> regs + LDS ----
    float x1r[CAP], y1r[CAP], x2r[CAP], y2r[CAP], ar[CAP];
    u64 key[CAP];
    const float4* boxes4 = reinterpret_cast<const float4*>(boxes);
    #pragma unroll
    for (int j = 0; j < CAP; ++j) {
        key[j] = 0;
        x1r[j] = 0.0f; y1r[j] = 0.0f; x2r[j] = 0.0f; y2r[j] = 0.0f; ar[j] = 0.0f;
        int r = tid + T * j;
        if (r < cnt) {
            int lo = 0, hi = 63;   // smallest word W with wordpref[W] > r
            while (lo < hi) { int mid = (lo + hi) >> 1; if (wordpref[mid] > (u32)r) hi = mid; else lo = mid + 1; }
            int W = lo;
            u32 rb = (W == 0) ? 0u : wordpref[W - 1];
            u32 t = (u32)r - rb;
            u64 x = maskw[W];
            int pos = 0;
            u32 c;
            c = (u32)__popcll(x & 0xFFFFFFFFull); if (t >= c) { pos += 32; t -= c; x >>= 32; }
            c = (u32)__popcll(x & 0xFFFFull);     if (t >= c) { pos += 16; t -= c; x >>= 16; }
            c = (u32)__popcll(x & 0xFFull);       if (t >= c) { pos += 8;  t -= c; x >>= 8; }
            c = (u32)__popcll(x & 0xFull);        if (t >= c) { pos += 4;  t -= c; x >>= 4; }
            c = (u32)__popcll(x & 0x3ull);        if (t >= c) { pos += 2;  t -= c; x >>= 2; }
            c = (u32)__popcll(x & 0x1ull);        if (t >= c) { pos += 1; }
            int g = W * 64 + pos;
            float4 b = boxes4[g];
            x1r[j] = b.x; y1r[j] = b.y; x2r[j] = b.z; y2r[j] = b.w;
            ar[j]  = __fmul_rn(__fsub_rn(b.z, b.x), __fsub_rn(b.w, b.y));
            float s = scores[g];
            // key: score<<32 | (4095-g)<<16 | r   (g: argmax tie-break; r: slot)
            key[j] = ((u64)__float_as_uint(s) << 32)
                   | ((u64)(u32)(4095 - g) << 16) | (u64)(u32)r;
            if (r < BOXCAP) box_lds[r] = b;
        }
    }
    __syncthreads();

    // ---- phase 1: guarded batch simulation, paired selections ----
    u64*    okey = WS_KEY(ws, cls);
    float4* obox = WS_BOX(ws, cls);
    const bool use_lds = (cnt <= BOXCAP);
    int mcnt = 0;

    for (int outer = 0; outer <= N_BOXES; ++outer) {   // cap: insurance only
        // gather: per-thread top-2 of live keys (u64, branchless)
        u64 m1 = 0, m2 = 0;
        #pragma unroll
        for (int j = 0; j < CAP; ++j) {
            if (T * j < cnt) {
                u64 kj  = key[j];
                u64 nm1 = kmax(m1, kj);
                m2 = kmax(m2, kmin(m1, kj));
                m1 = nm1;
            }
        }
        u64 wg = wave_max_u64(m2);
        if (lane == 0) redG[wid] = wg;
        cand[tid] = m1;
        __syncthreads();                               // B1: posts visible

        // level-2: lane keeps only its max of FOLD candidates; 2nd folds into G
        u64 c1 = 0, c2 = 0;
        #pragma unroll
        for (int q = 0; q < FOLD; ++q) {
            u64 c  = cand[lane + 64 * q];
            u64 n1 = kmax(c1, c);
            c2 = kmax(c2, kmin(c1, c));
            c1 = n1;
        }
        u64 Gr = redG[0];
        #pragma unroll
        for (int q = 1; q < NWAVE; ++q) Gr = kmax(Gr, redG[q]);
        u64 G = kmax(Gr, wave_max_u64(c2));
        const u32 Ghi = (u32)(G >> 32), Glo = (u32)G;

        u32 cscb = (u32)(c1 >> 32);                    // score bits (non-neg)
        u32 cst  = (u32)c1;                            // static (unique)
        float4 cb;
        if (use_lds) cb = box_lds[(int)(c1 & 0xFFFF)];
        else         cb = boxes4[4095 - (int)((c1 >> 16) & 0xFFFF)];
        float car = __fmul_rn(__fsub_rn(cb.z, cb.x), __fsub_rn(cb.w, cb.y));

        u32 hm[CAP];                                   // per-slot hit bitmasks
        #pragma unroll
        for (int j = 0; j < CAP; ++j) hm[j] = 0;

        int did = 0;
        for (;;) {
            // ---- winner 1: wave argmax on score bits (tie path rare) ----
            int h1 = wave_max_nonneg((int)cscb);
            const u32 uh1 = (u32)h1;
            if (uh1 == 0u) break;                      // all dead
            if (uh1 < Ghi) break;                      // guard (fast)
            u64 b1m = __ballot(cscb == uh1);
            u32 ul1; int src1;
            if (__popcll(b1m) == 1) {
                src1 = (int)__builtin_ctzll(b1m);
                ul1  = (u32)__builtin_amdgcn_readlane((int)cst, src1);
            } else {
                int lom = (cscb == uh1) ? (int)cst : 0;
                ul1 = (u32)wave_max_nonneg(lom);
                src1 = (int)__builtin_ctzll(__ballot((cscb == uh1) & (cst == ul1)));
            }
            if (uh1 == Ghi && ul1 <= Glo) break;       // guard (exact)
            if (did == BMAX) break;                    // mask width

            float w1x1 = readlane_f(cb.x, src1);
            float w1y1 = readlane_f(cb.y, src1);
            float w1x2 = readlane_f(cb.z, src1);
            float w1y2 = readlane_f(cb.w, src1);
            float war1 = readlane_f(car,  src1);

            // ---- winner 2 (speculative): masked runner-up ----
            u32 csc2 = (lane == src1) ? 0u : cscb;
            int h2 = wave_max_nonneg((int)csc2);
            const u32 uh2 = (u32)h2;
            bool take2 = false; int src2 = 0; u32 ul2 = 0;
            float w2x1 = 0.0f, w2y1 = 0.0f, w2x2 = 0.0f, w2y2 = 0.0f, war2 = 0.0f;
            if (uh2 != 0u && uh2 >= Ghi && (did + 1) < BMAX) {
                u64 b2m = __ballot(csc2 == uh2);
                if (__popcll(b2m) == 1) {
                    src2 = (int)__builtin_ctzll(b2m);
                    ul2  = (u32)__builtin_amdgcn_readlane((int)cst, src2);
                } else {
                    int lom2 = (csc2 == uh2) ? (int)cst : 0;
                    ul2 = (u32)wave_max_nonneg(lom2);
                    src2 = (int)__builtin_ctzll(__ballot((csc2 == uh2) & (cst == ul2)));
                }
                if (uh2 > Ghi || ul2 > Glo) {
                    w2x1 = readlane_f(cb.x, src2);
                    w2y1 = readlane_f(cb.y, src2);
                    w2x2 = readlane_f(cb.z, src2);
                    w2y2 = readlane_f(cb.w, src2);
                    war2 = readlane_f(car,  src2);
                    // pair valid iff boxes disjoint (covers all ranking-change cases)
                    bool ovl = (w1x2 > w2x1) & (w2x2 > w1x1)
                             & (w1y2 > w2y1) & (w2y2 > w1y1);
                    take2 = !ovl;
                }
            }

            // ---- stage winners: LDS batch arrays + output keys (tid0) ----
            if (tid == 0) {
                u64 w1k = ((u64)uh1 << 32) | (u64)ul1;
                batchbox[did]  = make_float4(w1x1, w1y1, w1x2, w1y2);
                batchstat[did] = ul1;
                if (use_lds) { if (mcnt < BOXCAP) okey_lds[mcnt] = w1k; }
                else if (mcnt < N_BOXES) { okey[mcnt] = w1k; obox[mcnt] = make_float4(w1x1, w1y1, w1x2, w1y2); }
                if (take2) {
                    u64 w2k = ((u64)uh2 << 32) | (u64)ul2;
                    batchbox[did + 1]  = make_float4(w2x1, w2y1, w2x2, w2y2);
                    batchstat[did + 1] = ul2;
                    if (use_lds) { if (mcnt + 1 < BOXCAP) okey_lds[mcnt + 1] = w2k; }
                    else if (mcnt + 1 < N_BOXES) { okey[mcnt + 1] = w2k; obox[mcnt + 1] = make_float4(w2x1, w2y1, w2x2, w2y2); }
                }
            }

            // ---- candidate decay: ballot-gated d1/d2, applied in order ----
            float i1x1 = fmaxf(w1x1, cb.x);
            float i1y1 = fmaxf(w1y1, cb.y);
            float i1x2 = fminf(w1x2, cb.z);
            float i1y2 = fminf(w1y2, cb.w);
            float iw1  = fmaxf(__fsub_rn(i1x2, i1x1), 0.0f);
            float ih1  = fmaxf(__fsub_rn(i1y2, i1y1), 0.0f);
            float int1 = __fmul_rn(iw1, ih1);
            float s0 = __uint_as_float(cscb);
            float a1;
            // skip div+exp when no live non-winner candidate overlaps winner1:
            // then a1 = s0 bitwise for every lane (winner zeroed below). Exact.
            u64 ob1 = __ballot((int1 > 0.0f) & (lane != src1));
            if (ob1 != 0) {
                float den1 = __fadd_rn(__fsub_rn(__fadd_rn(war1, car), int1), 1e-8f);
                float iou1 = int1 / den1;                    // IEEE div
                float d1   = expf(__fmul_rn(-2.0f, __fmul_rn(iou1, iou1)));
                float n1 = __fmul_rn(s0, d1);
                float k1 = (n1 >= SCORE_THR) ? n1 : 0.0f;
                a1 = (int1 > 0.0f) ? k1 : s0;
            } else {
                a1 = s0;
            }
            a1 = (lane == src1) ? 0.0f : a1;
            float res = a1;

            if (take2) {
                float i2x1 = fmaxf(w2x1, cb.x);
                float i2y1 = fmaxf(w2y1, cb.y);
                float i2x2 = fminf(w2x2, cb.z);
                float i2y2 = fminf(w2y2, cb.w);
                float iw2  = fmaxf(__fsub_rn(i2x2, i2x1), 0.0f);
                float ih2  = fmaxf(__fsub_rn(i2y2, i2y1), 0.0f);
                float int2 = __fmul_rn(iw2, ih2);
                float a2;
                u64 ob2 = __ballot((int2 > 0.0f) & (lane != src2));
                if (ob2 != 0) {
                    float den2 = __fadd_rn(__fsub_rn(__fadd_rn(war2, car), int2), 1e-8f);
                    float iou2 = int2 / den2;                // IEEE div
                    float d2   = expf(__fmul_rn(-2.0f, __fmul_rn(iou2, iou2)));
                    float n2 = __fmul_rn(a1, d2);
                    float k2 = (n2 >= SCORE_THR) ? n2 : 0.0f;
                    a2 = (int2 > 0.0f) ? k2 : a1;
                } else {
                    a2 = a1;
                }
                res = (lane == src2) ? 0.0f : a2;
            }
            cscb = __float_as_uint(res);

            // ---- owned-slot hit bits (bodies deferred to replay) ----
            u32 bit1 = 1u << did;
            u32 bit2 = (take2 ? (2u << did) : 0u);
            #pragma unroll
            for (int j = 0; j < CAP; ++j) {
                if (T * j < cnt) {
                    bool hit1 = (w1x2 > x1r[j]) & (x2r[j] > w1x1)
                              & (w1y2 > y1r[j]) & (y2r[j] > w1y1);
                    u32 h = hit1 ? bit1 : 0u;
                    if (take2) {
                        bool hit2 = (w2x2 > x1r[j]) & (x2r[j] > w2x1)
                                  & (w2y2 > y1r[j]) & (y2r[j] > w2y1);
                        h |= hit2 ? bit2 : 0u;
                    }
                    hm[j] |= h;
                }
            }
            int adv = take2 ? 2 : 1;
            mcnt += adv; did += adv;
        }
        if (did == 0) break;                           // all keys dead
        __syncthreads();                               // B2: batch arrays visible

        // ---- replay: full exact body on set bits, ascending batch order ----
        // divergent LDS reads (well-defined), R12-proven structure
        #pragma unroll
        for (int j = 0; j < CAP; ++j) {
            if (T * j < cnt) {
                u32 m = hm[j];
                while (m) {
                    int b = (int)__builtin_ctz(m);
                    m &= (m - 1);
                    float4 wb = batchbox[b];
                    u32   wst = batchstat[b];
                    float wx1 = wb.x, wy1 = wb.y, wx2 = wb.z, wy2 = wb.w;
                    float warea = __fmul_rn(__fsub_rn(wx2, wx1), __fsub_rn(wy2, wy1));
                    u64 kj = key[j];
                    float ix1   = fmaxf(wx1, x1r[j]);
                    float iy1   = fmaxf(wy1, y1r[j]);
                    float ix2   = fminf(wx2, x2r[j]);
                    float iy2   = fminf(wy2, y2r[j]);
                    float iw    = fmaxf(__fsub_rn(ix2, ix1), 0.0f);
                    float ih    = fmaxf(__fsub_rn(iy2, iy1), 0.0f);
                    float inter = __fmul_rn(iw, ih);
                    float denom = __fadd_rn(__fsub_rn(__fadd_rn(warea, ar[j]), inter), 1e-8f);
                    float iou   = inter / denom;                // IEEE div
                    float t2    = __fmul_rn(iou, iou);
                    float decay = expf(__fmul_rn(-2.0f, t2));   // exp(-iou^2/0.5)
                    float sc    = __uint_as_float((u32)(kj >> 32));
                    float ns    = __fmul_rn(sc, decay);
                    bool  app   = (kj != 0) && (inter > 0.0f);
                    u64   nk    = ((u64)__float_as_uint(ns) << 32) | (kj & 0xFFFFFFFFull);
                    u64   upd   = app ? ((ns >= SCORE_THR) ? nk : 0ull) : kj;
                    key[j] = ((u32)kj == wst) ? 0ull : upd;     // winner-zero (static unique)
                }
            }
        }
    }

    // ---- batched flush of staged winners (boxes recovered by rank) ----
    int mfin = (mcnt <= cnt) ? mcnt : cnt;             // clamp: insurance only
    if (use_lds) {
        __syncthreads();
        int fl = (mfin <= BOXCAP) ? mfin : BOXCAP;
        for (int m = tid; m < fl; m += T) {
            u64 w = okey_lds[m];
            okey[m] = w;
            obox[m] = box_lds[(int)(w & 0xFFFF)];
        }
    }
    if (tid == 0) WS_CNT(ws)[cls] = mfin;
}

// merge the two strictly-descending key lists by rank; pad the tail
__global__ void softnms_merge(void* __restrict__ ws, float* __restrict__ out) {
    int k = blockIdx.x * blockDim.x + threadIdx.x;   // 0..4095
    const u64*    keyA = WS_KEY(ws, 0);
    const u64*    keyB = WS_KEY(ws, 1);
    const float4* boxA = WS_BOX(ws, 0);
    const float4* boxB = WS_BOX(ws, 1);
    const int mA = WS_CNT(ws)[0];
    const int mB = WS_CNT(ws)[1];

    float* ob = out;
    float* os = out + N_BOXES * 4;
    float* ol = out + N_BOXES * 5;

    if (k < mA) {
        u64 x = keyA[k];
        int lo = 0, hi = mB;
        while (lo < hi) { int mid = (lo + hi) >> 1; if (keyB[mid] > x) lo = mid + 1; else hi = mid; }
        int pos = k + lo;
        float4 b = boxA[k];
        ob[pos * 4 + 0] = b.x; ob[pos * 4 + 1] = b.y;
        ob[pos * 4 + 2] = b.z; ob[pos * 4 + 3] = b.w;
        os[pos] = __uint_as_float((u32)(x >> 32));
        ol[pos] = 0.0f;
    } else if (k < mA + mB) {
        int i = k - mA;
        u64 x = keyB[i];
        int lo = 0, hi = mA;
        while (lo < hi) { int mid = (lo + hi) >> 1; if (keyA[mid] > x) lo = mid + 1; else hi = mid; }
        int pos = i + lo;
        float4 b = boxB[i];
        ob[pos * 4 + 0] = b.x; ob[pos * 4 + 1] = b.y;
        ob[pos * 4 + 2] = b.z; ob[pos * 4 + 3] = b.w;
        os[pos] = __uint_as_float((u32)(x >> 32));
        ol[pos] = 1.0f;
    } else {
        ob[k * 4 + 0] = 0.0f; ob[k * 4 + 1] = 0.0f;
        ob[k * 4 + 2] = 0.0f; ob[k * 4 + 3] = 0.0f;
        os[k] = 0.0f;
        ol[k] = -1.0f;
    }
}

extern "C" void kernel_launch(void* const* d_in, const int* in_sizes, int n_in,
                              void* d_out, int out_size, void* d_ws, size_t ws_size,
                              hipStream_t stream) {
    const float* boxes  = (const float*)d_in[0];
    const float* scores = (const float*)d_in[1];
    const int*   labels = (const int*)d_in[2];
    float* out = (float*)d_out;
    (void)in_sizes; (void)n_in; (void)out_size; (void)ws_size;
    softnms_fused<<<2, T, 0, stream>>>(boxes, scores, labels, d_ws);
    softnms_merge<<<N_BOXES / 256, 256, 0, stream>>>(d_ws, out);
}